// Round 1
// baseline (292.327 us; speedup 1.0000x reference)
//
#include <hip/hip_runtime.h>
#include <math.h>

// Problem constants (fixed shapes from setup_inputs).
#define NB   64     // batch
#define CIN  64
#define COUT 64
#define HH   112
#define WW   112
#define KH   3
#define KW   3
#define MAXE (CIN*KH*KW)   // 576 possible nonzero weight entries per out-channel

// ---------------------------------------------------------------------------
// Kernel A: ternarize weights, compact nonzero entries per out-channel.
// ws layout: int nnz[COUT]; int entries[COUT][MAXE];
// entry: bit31 = sign (1 => -1), bits[9:4]=ci, bits[3:2]=kh, bits[1:0]=kw
// One block per co, 576 threads (9 waves). LDS counter -> no global init needed.
// ---------------------------------------------------------------------------
__global__ void ternarize_compact_kernel(const float* __restrict__ w,
                                         int* __restrict__ nnz,
                                         int* __restrict__ entries) {
    __shared__ int cnt;
    const int co = blockIdx.x;
    if (threadIdx.x == 0) cnt = 0;
    __syncthreads();

    const int t  = threadIdx.x;          // 0..575
    const int ci = t / 9;
    const int r  = t - ci * 9;
    const int kh = r / 3;
    const int kw = r - kh * 3;

    const float wv = w[((co * CIN + ci) * KH + kh) * KW + kw];
    // jnp.round is round-half-to-even -> rintf (default FE_TONEAREST) matches.
    const int tv = (int)rintf(tanhf(wv));   // -1, 0, +1

    if (tv != 0) {
        const int idx = atomicAdd(&cnt, 1);           // LDS atomic, block-local
        int packed = (ci << 4) | (kh << 2) | kw;
        if (tv < 0) packed |= (int)0x80000000;
        entries[co * MAXE + idx] = packed;
    }
    __syncthreads();
    if (threadIdx.x == 0) nnz[co] = cnt;
    // Order within the list is nondeterministic, but every partial sum of
    // +/-1 terms (|sum| <= 576) is an exact fp32 integer -> result exact.
}

// ---------------------------------------------------------------------------
// Kernel B: sparse ternary conv. One thread -> 4 contiguous output pixels
// (float4 store). Loops only over the nonzero entries for its out-channel.
// With nnz == 0 this is a pure coalesced zero-store (alpha * 0).
// ---------------------------------------------------------------------------
__global__ void __launch_bounds__(256)
sparse_tern_conv_kernel(const float* __restrict__ x,
                        const float* __restrict__ alpha,
                        const int* __restrict__ nnz,
                        const int* __restrict__ entries,
                        float* __restrict__ out) {
    // Flat index over [NB][COUT][HH][WW/4] = 64*64*112*28 = 12,845,056
    const int i  = blockIdx.x * 256 + threadIdx.x;
    const int w4 = i % 28;
    int t        = i / 28;
    const int h  = t % HH;
    t            = t / HH;
    const int co = t % COUT;
    const int n  = t / COUT;
    const int w0 = w4 * 4;

    const int cnt = nnz[co];
    float a0 = 0.f, a1 = 0.f, a2 = 0.f, a3 = 0.f;

    if (cnt > 0) {
        const float* __restrict__ xn = x + (size_t)n * (CIN * HH * WW);
        const int*   __restrict__ ep = entries + co * MAXE;
        for (int e = 0; e < cnt; ++e) {
            const int p  = ep[e];
            const float s = (p < 0) ? -1.f : 1.f;
            const int q  = p & 0x7fffffff;
            const int ci = q >> 4;
            const int kh = (q >> 2) & 3;
            const int kw = q & 3;
            const int hy = h + kh - 1;
            if ((unsigned)hy >= (unsigned)HH) continue;   // zero padding row
            const float* __restrict__ row = xn + (ci * HH + hy) * WW;
            const int wx = w0 + kw - 1;
            #pragma unroll
            for (int j = 0; j < 4; ++j) {
                const int wj = wx + j;
                if ((unsigned)wj < (unsigned)WW) {        // zero padding col
                    const float xv = row[wj];
                    // sign(): must map exact 0 (and -0) to 0
                    const float sg = (xv > 0.f) ? 1.f : ((xv < 0.f) ? -1.f : 0.f);
                    const float c  = s * sg;
                    if (j == 0) a0 += c;
                    else if (j == 1) a1 += c;
                    else if (j == 2) a2 += c;
                    else a3 += c;
                }
            }
        }
    }

    const float al = alpha[co];
    float4 o;
    o.x = a0 * al; o.y = a1 * al; o.z = a2 * al; o.w = a3 * al;
    reinterpret_cast<float4*>(out)[i] = o;
}

// ---------------------------------------------------------------------------
extern "C" void kernel_launch(void* const* d_in, const int* in_sizes, int n_in,
                              void* d_out, int out_size, void* d_ws, size_t ws_size,
                              hipStream_t stream) {
    const float* x      = (const float*)d_in[0];   // [64,64,112,112]
    const float* weight = (const float*)d_in[1];   // [64,64,3,3]
    const float* alpha  = (const float*)d_in[2];   // [64,1,1]
    float*       out    = (float*)d_out;

    int* nnz     = (int*)d_ws;                     // COUT ints
    int* entries = nnz + COUT;                     // COUT*MAXE ints (~147 KB total)

    ternarize_compact_kernel<<<COUT, MAXE, 0, stream>>>(weight, nnz, entries);

    const int total4 = NB * COUT * HH * (WW / 4);  // 12,845,056
    sparse_tern_conv_kernel<<<total4 / 256, 256, 0, stream>>>(x, alpha, nnz, entries, out);
}